// Round 4
// baseline (67.517 us; speedup 1.0000x reference)
//
#include <hip/hip_runtime.h>

// SymbolicTraversal: out[b, n] = max(0, max_{e: type[e]==r_index[b], dst[e]==n} h[b, src[e]])
//
// R3: two-phase dst-bucketed scatter.
//   Phase 1: stream edges, filter by relation->batch bitmask, compact (b,src,dst)
//            into 8 dst-range buckets in ws (LDS-staged, coalesced appends,
//            replicated counters). Pure streaming, no scattered traffic.
//   Phase 2: blockIdx%8 -> bucket (XCD round-robin heuristic) so all atomics to a
//            given out-slice come from one XCD and stay in its local L2.
// Correctness never depends on XCD mapping or ws capacity (overflow -> direct atomicMax).
// atomicMax is unconditional: signed-int compare vs init 0 makes v<=0 a no-op.

typedef int v4i __attribute__((ext_vector_type(4)));

#define NBUCKET 8
#define NREP 32
#define QCAP 384
#define P2_CHUNKS 128

__global__ __launch_bounds__(256)
void zero_out_kernel(float4* __restrict__ out, int n4) {
    int i = blockIdx.x * blockDim.x + threadIdx.x;
    if (i < n4) {
        float4 z; z.x = 0.f; z.y = 0.f; z.z = 0.f; z.w = 0.f;
        out[i] = z;
    }
}

__global__ __launch_bounds__(256)
void zero_ctr_kernel(unsigned int* __restrict__ gcnt) {
    int i = threadIdx.x;
    if (i < NBUCKET * NREP) gcnt[i * 16] = 0;  // one counter per 64B line
}

__device__ __forceinline__ void direct_update(const float* __restrict__ h,
                                              int* __restrict__ out,
                                              int b, int s, int d, int N) {
    float v = h[(size_t)b * N + s];
    atomicMax(out + (size_t)b * N + d, __float_as_int(v));
}

__global__ __launch_bounds__(256)
void phase1_kernel(const int* __restrict__ edge_index, // [2][E]
                   const int* __restrict__ etype,      // [E]
                   const int* __restrict__ r_index,    // [B]
                   const float* __restrict__ h,
                   int* __restrict__ out,              // only for overflow fallback
                   unsigned int* __restrict__ gcnt,    // counters, stride 16 u32
                   uint2* __restrict__ store,          // bucket storage
                   int capr, int B, int N, int E, int bsize) {
    __shared__ unsigned int smask[64];
    __shared__ unsigned int lcnt[NBUCKET];
    __shared__ unsigned int lbase[NBUCKET];
    __shared__ uint2 lq[NBUCKET][QCAP];

    if (threadIdx.x < 64) {
        unsigned int m = 0;
        for (int b = 0; b < B; ++b)
            if (r_index[b] == (int)threadIdx.x) m |= (1u << b);
        smask[threadIdx.x] = m;
    }
    if (threadIdx.x < NBUCKET) lcnt[threadIdx.x] = 0;
    __syncthreads();

    const int* __restrict__ src = edge_index;
    const int* __restrict__ dst = edge_index + E;
    const int rep = blockIdx.x & (NREP - 1);

    int tid = blockIdx.x * blockDim.x + threadIdx.x;
    int e0 = tid * 4;

    int tt[4], ss[4], dd[4];
    if (e0 + 3 < E) {
        v4i t = __builtin_nontemporal_load(reinterpret_cast<const v4i*>(etype + e0));
        v4i s = __builtin_nontemporal_load(reinterpret_cast<const v4i*>(src + e0));
        v4i d = __builtin_nontemporal_load(reinterpret_cast<const v4i*>(dst + e0));
        #pragma unroll
        for (int i = 0; i < 4; ++i) { tt[i] = t[i]; ss[i] = s[i]; dd[i] = d[i]; }
    } else {
        #pragma unroll
        for (int i = 0; i < 4; ++i) {
            int e = e0 + i;
            if (e < E) { tt[i] = etype[e]; ss[i] = src[e]; dd[i] = dst[e]; }
            else       { tt[i] = -1; ss[i] = 0; dd[i] = 0; }
        }
    }

    #pragma unroll
    for (int i = 0; i < 4; ++i) {
        unsigned int ty = (unsigned int)tt[i];
        unsigned int m = (ty < 64u) ? smask[ty] : 0u;
        while (m) {
            int b = __builtin_ctz(m);
            m &= m - 1;
            int bkt = dd[i] / bsize; if (bkt > NBUCKET - 1) bkt = NBUCKET - 1;
            unsigned int pos = atomicAdd(&lcnt[bkt], 1u);
            uint2 rec; rec.x = ((unsigned int)dd[i] << 5) | (unsigned int)b;
            rec.y = (unsigned int)ss[i];
            if (pos < QCAP) {
                lq[bkt][pos] = rec;
            } else {
                unsigned int g = atomicAdd(&gcnt[(bkt * NREP + rep) * 16], 1u);
                if (g < (unsigned int)capr)
                    store[(size_t)(bkt * NREP + rep) * capr + g] = rec;
                else
                    direct_update(h, out, b, ss[i], dd[i], N);
            }
        }
    }

    __syncthreads();
    if (threadIdx.x < NBUCKET) {
        unsigned int n = lcnt[threadIdx.x]; if (n > QCAP) n = QCAP;
        lbase[threadIdx.x] = atomicAdd(&gcnt[(threadIdx.x * NREP + rep) * 16], n);
    }
    __syncthreads();

    for (int bkt = 0; bkt < NBUCKET; ++bkt) {
        unsigned int n = lcnt[bkt]; if (n > QCAP) n = QCAP;
        unsigned int base = lbase[bkt];
        uint2* __restrict__ dsts = store + (size_t)(bkt * NREP + rep) * capr;
        for (unsigned int i = threadIdx.x; i < n; i += blockDim.x) {
            unsigned int g = base + i;
            uint2 rec = lq[bkt][i];
            if (g < (unsigned int)capr) {
                dsts[g] = rec;
            } else {
                int b = rec.x & 31; int d = rec.x >> 5; int s = rec.y;
                direct_update(h, out, b, s, d, N);
            }
        }
    }
}

__global__ __launch_bounds__(256)
void phase2_kernel(const float* __restrict__ h,
                   const uint2* __restrict__ store,
                   const unsigned int* __restrict__ gcnt,
                   int capr, int N,
                   int* __restrict__ out) {
    __shared__ unsigned int pfx[NREP + 1];
    const int bkt = blockIdx.x & (NBUCKET - 1);
    const int chunk = blockIdx.x >> 3;  // 0..P2_CHUNKS-1

    if (threadIdx.x == 0) {
        unsigned int acc = 0;
        pfx[0] = 0;
        for (int r = 0; r < NREP; ++r) {
            unsigned int c = gcnt[(bkt * NREP + r) * 16];
            if (c > (unsigned int)capr) c = capr;
            acc += c;
            pfx[r + 1] = acc;
        }
    }
    __syncthreads();

    const unsigned int total = pfx[NREP];
    const unsigned int span = (total + P2_CHUNKS - 1) / P2_CHUNKS;
    unsigned int g0 = (unsigned int)chunk * span;
    unsigned int g1 = g0 + span; if (g1 > total) g1 = total;

    for (unsigned int g = g0 + threadIdx.x; g < g1; g += blockDim.x) {
        // binary search rep: largest r with pfx[r] <= g
        int lo = 0, hi = NREP;
        while (hi - lo > 1) {
            int mid = (lo + hi) >> 1;
            if (pfx[mid] <= g) lo = mid; else hi = mid;
        }
        unsigned int li = g - pfx[lo];
        uint2 rec = store[(size_t)(bkt * NREP + lo) * capr + li];
        int b = rec.x & 31;
        int d = rec.x >> 5;
        int s = rec.y;
        float v = h[(size_t)b * N + s];
        atomicMax(out + (size_t)b * N + d, __float_as_int(v));
    }
}

extern "C" void kernel_launch(void* const* d_in, const int* in_sizes, int n_in,
                              void* d_out, int out_size, void* d_ws, size_t ws_size,
                              hipStream_t stream) {
    const float* h          = (const float*)d_in[0];
    const int*   edge_index = (const int*)d_in[1];
    const int*   etype      = (const int*)d_in[2];
    const int*   r_index    = (const int*)d_in[3];

    const int B = in_sizes[3];
    const int N = in_sizes[0] / B;
    const int E = in_sizes[2];
    const int bsize = (N + NBUCKET - 1) / NBUCKET;

    // ws layout: [0, 16KB) counters (8*32, one per 64B line); rest = bucket storage
    unsigned int* gcnt = (unsigned int*)d_ws;
    const size_t ctr_bytes = NBUCKET * NREP * 64;
    uint2* store = (uint2*)((char*)d_ws + ctr_bytes);
    long long cap_ll = 0;
    if (ws_size > ctr_bytes)
        cap_ll = (long long)((ws_size - ctr_bytes) / sizeof(uint2)) / (NBUCKET * NREP);
    const int capr = (int)(cap_ll > 0x7fffffffLL ? 0x7fffffffLL : cap_ll);

    zero_ctr_kernel<<<1, 256, 0, stream>>>(gcnt);
    const int n4 = out_size / 4;
    zero_out_kernel<<<(n4 + 255) / 256, 256, 0, stream>>>((float4*)d_out, n4);

    const int threads = 256;
    const int nquads  = (E + 3) / 4;
    const int blocks  = (nquads + threads - 1) / threads;
    phase1_kernel<<<blocks, threads, 0, stream>>>(
        edge_index, etype, r_index, h, (int*)d_out, gcnt, store,
        capr, B, N, E, bsize);

    phase2_kernel<<<NBUCKET * P2_CHUNKS, 256, 0, stream>>>(
        h, store, gcnt, capr, N, (int*)d_out);
}

// Round 5
// 48.259 us; speedup vs baseline: 1.3991x; 1.3991x over previous
//
#include <hip/hip_runtime.h>

// SymbolicTraversal: out[b, n] = max(0, max_{e: type[e]==r_index[b], dst[e]==n} h[b, src[e]])
//
// R4: eliminate global atomics. Bucket matching edges by (batch, dst>>13) so each
// bucket's output slice (8192 floats = 32KB) fits in LDS. Phase 2 resolves the
// segment-max with LDS atomics and writes out with plain coalesced stores.
// Records are 4B: ((dst & 8191) << 17) | src   (requires N <= 2^17; guarded).
// Overflow (ws too small / LDS queue full) falls back to device atomicMax into the
// zero-initialized out; phase2 merges (max) with existing out, so any overflow mix
// is still exact. Correct for any ws_size; fast path needs the ~256MB ws we have.

typedef int v4i __attribute__((ext_vector_type(4)));

#define TH1 512
#define NB1 512
#define TH2 512
#define QCAP 64
#define MAXBKT 256
#define CSHIFT 13

__global__ __launch_bounds__(256)
void zero_out_kernel(int* __restrict__ out, int n) {
    int i = (blockIdx.x * 256 + threadIdx.x) * 4;
    if (i + 3 < n) {
        v4i z = {0, 0, 0, 0};
        *reinterpret_cast<v4i*>(out + i) = z;
    } else {
        for (int j = i; j < n; ++j) out[j] = 0;
    }
}

__global__ __launch_bounds__(256)
void zero_ctr_kernel(unsigned int* __restrict__ gcnt, int nwords) {
    for (int i = threadIdx.x; i < nwords; i += 256) gcnt[i] = 0;
}

__global__ __launch_bounds__(TH1)
void phase1_kernel(const int* __restrict__ edge_index, // [2][E]
                   const int* __restrict__ etype,      // [E]
                   const int* __restrict__ r_index,    // [B]
                   const float* __restrict__ h,
                   int* __restrict__ out,              // overflow fallback only
                   unsigned int* __restrict__ gcnt,    // per-bucket counters, stride 16
                   unsigned int* __restrict__ store,   // bucket storage
                   int capr, int B, int N, int E,
                   int nchunk, int nbkt) {
    __shared__ unsigned int smask[64];
    __shared__ unsigned int lcnt[MAXBKT];
    __shared__ unsigned int lbase[MAXBKT];
    __shared__ unsigned int lq[MAXBKT * QCAP];

    const int t = threadIdx.x;
    if (t < 64) {
        unsigned int m = 0;
        for (int b = 0; b < B; ++b)
            if (r_index[b] == t) m |= (1u << b);
        smask[t] = m;
    }
    for (int i = t; i < nbkt; i += TH1) lcnt[i] = 0;
    __syncthreads();

    const int* __restrict__ src = edge_index;
    const int* __restrict__ dst = edge_index + E;
    const unsigned int cmask = (1u << CSHIFT) - 1u;
    const int nq = E >> 2;

    for (int q = blockIdx.x * TH1 + t; q < nq; q += NB1 * TH1) {
        v4i tv = __builtin_nontemporal_load(reinterpret_cast<const v4i*>(etype) + q);
        v4i sv = __builtin_nontemporal_load(reinterpret_cast<const v4i*>(src) + q);
        v4i dv = __builtin_nontemporal_load(reinterpret_cast<const v4i*>(dst) + q);
        #pragma unroll
        for (int i = 0; i < 4; ++i) {
            unsigned int ty = (unsigned int)tv[i];
            unsigned int m = (ty < 64u) ? smask[ty] : 0u;
            if (!m) continue;
            unsigned int d = (unsigned int)dv[i];
            unsigned int s = (unsigned int)sv[i];
            unsigned int rec = ((d & cmask) << 17) | s;
            int cb = (int)(d >> CSHIFT);
            do {
                int b = __builtin_ctz(m); m &= m - 1;
                int bkt = b * nchunk + cb;
                unsigned int pos = atomicAdd(&lcnt[bkt], 1u);
                if (pos < QCAP) {
                    lq[bkt * QCAP + pos] = rec;
                } else {
                    unsigned int g = atomicAdd(&gcnt[bkt * 16], 1u);
                    if (g < (unsigned int)capr) {
                        store[(size_t)bkt * capr + g] = rec;
                    } else {
                        float v = h[(size_t)b * N + s];
                        atomicMax(out + (size_t)b * N + d, __float_as_int(v));
                    }
                }
            } while (m);
        }
    }
    // tail edges (E % 4), block 0 only
    if (blockIdx.x == 0) {
        for (int e = (nq << 2) + t; e < E; e += TH1) {
            unsigned int ty = (unsigned int)etype[e];
            unsigned int m = (ty < 64u) ? smask[ty] : 0u;
            unsigned int d = (unsigned int)dst[e];
            unsigned int s = (unsigned int)src[e];
            unsigned int rec = ((d & cmask) << 17) | s;
            int cb = (int)(d >> CSHIFT);
            while (m) {
                int b = __builtin_ctz(m); m &= m - 1;
                int bkt = b * nchunk + cb;
                unsigned int pos = atomicAdd(&lcnt[bkt], 1u);
                if (pos < QCAP) {
                    lq[bkt * QCAP + pos] = rec;
                } else {
                    unsigned int g = atomicAdd(&gcnt[bkt * 16], 1u);
                    if (g < (unsigned int)capr)
                        store[(size_t)bkt * capr + g] = rec;
                    else {
                        float v = h[(size_t)b * N + s];
                        atomicMax(out + (size_t)b * N + d, __float_as_int(v));
                    }
                }
            }
        }
    }

    __syncthreads();
    for (int k = t; k < nbkt; k += TH1) {
        unsigned int n = lcnt[k]; if (n > QCAP) n = QCAP;
        lbase[k] = atomicAdd(&gcnt[k * 16], n);
    }
    __syncthreads();
    // coalesced flush: one wave per bucket, lane i writes record i (QCAP == 64)
    const int wid = t >> 6, lane = t & 63;
    for (int k = wid; k < nbkt; k += TH1 / 64) {
        unsigned int n = lcnt[k]; if (n > QCAP) n = QCAP;
        if ((unsigned int)lane < n)
            store[(size_t)k * capr + lbase[k] + lane] = lq[k * QCAP + lane];
    }
}

__global__ __launch_bounds__(TH2)
void phase2_kernel(const float* __restrict__ h,
                   const unsigned int* __restrict__ store,
                   const unsigned int* __restrict__ gcnt,
                   int capr, int N, int nchunk,
                   int* __restrict__ out) {
    __shared__ int slice[1 << CSHIFT];  // 32KB

    const int t = threadIdx.x;
    const int k = blockIdx.x;
    const int b = k / nchunk;
    const int c = k % nchunk;
    const int csz = 1 << CSHIFT;

    for (int i = t; i < csz; i += TH2) slice[i] = 0;
    __syncthreads();

    unsigned int n = gcnt[k * 16];
    if (n > (unsigned int)capr) n = (unsigned int)capr;
    const unsigned int* __restrict__ rp = store + (size_t)k * capr;
    const float* __restrict__ hb = h + (size_t)b * N;

    for (unsigned int i = t; i < n; i += TH2) {
        unsigned int rec = rp[i];
        int s  = (int)(rec & 0x1FFFFu);
        int ld = (int)(rec >> 17);
        float v = hb[s];
        atomicMax(&slice[ld], __float_as_int(v));  // LDS atomic, no fabric
    }
    __syncthreads();

    const int d0 = c << CSHIFT;
    int cnt = N - d0; if (cnt > csz) cnt = csz;
    int* __restrict__ ob = out + (size_t)b * N + d0;
    for (int i = t; i < cnt; i += TH2) {
        int cur = ob[i];          // out pre-zeroed; holds overflow-fallback results
        int v = slice[i];
        ob[i] = cur > v ? cur : v;
    }
}

// Fallback: direct single-pass kernel (R1 structure) for shapes the fast path
// doesn't support (N > 2^17, B > 32, or too many buckets).
__global__ __launch_bounds__(256)
void traverse_direct(const float* __restrict__ h,
                     const int* __restrict__ edge_index,
                     const int* __restrict__ etype,
                     const int* __restrict__ r_index,
                     int* __restrict__ out, int B, int N, int E) {
    __shared__ unsigned int smask[64];
    if (threadIdx.x < 64) {
        unsigned int m = 0;
        for (int b = 0; b < B; ++b)
            if (r_index[b] == (int)threadIdx.x) m |= (1u << b);
        smask[threadIdx.x] = m;
    }
    __syncthreads();
    const int* __restrict__ src = edge_index;
    const int* __restrict__ dst = edge_index + E;
    int e = blockIdx.x * blockDim.x + threadIdx.x;
    if (e < E) {
        unsigned int ty = (unsigned int)etype[e];
        unsigned int m = (ty < 64u) ? smask[ty] : 0u;
        while (m) {
            int b = __builtin_ctz(m); m &= m - 1;
            float v = h[(size_t)b * N + src[e]];
            atomicMax(out + (size_t)b * N + dst[e], __float_as_int(v));
        }
    }
}

extern "C" void kernel_launch(void* const* d_in, const int* in_sizes, int n_in,
                              void* d_out, int out_size, void* d_ws, size_t ws_size,
                              hipStream_t stream) {
    const float* h          = (const float*)d_in[0];
    const int*   edge_index = (const int*)d_in[1];
    const int*   etype      = (const int*)d_in[2];
    const int*   r_index    = (const int*)d_in[3];

    const int B = in_sizes[3];
    const int N = in_sizes[0] / B;
    const int E = in_sizes[2];

    const int nchunk = (N + (1 << CSHIFT) - 1) >> CSHIFT;
    const int nbkt = B * nchunk;

    unsigned int* gcnt = (unsigned int*)d_ws;
    const size_t ctr_bytes = (size_t)(nbkt > 0 ? nbkt : 1) * 64;
    unsigned int* store = (unsigned int*)((char*)d_ws + ctr_bytes);
    long long cap_ll = (ws_size > ctr_bytes)
        ? (long long)((ws_size - ctr_bytes) / 4) / (nbkt > 0 ? nbkt : 1) : 0;
    const int capr = (int)(cap_ll > 0x7fffffffLL ? 0x7fffffffLL : cap_ll);

    // zero out (needed by both paths: clamp floor + empty segments + merge base)
    const int nz = (out_size + 1023) / 1024;
    zero_out_kernel<<<nz, 256, 0, stream>>>((int*)d_out, out_size);

    const bool fast = (N <= (1 << 17)) && (B <= 32) && (nbkt >= 1) &&
                      (nbkt <= MAXBKT) && (capr > 0);
    if (fast) {
        zero_ctr_kernel<<<1, 256, 0, stream>>>(gcnt, nbkt * 16);
        phase1_kernel<<<NB1, TH1, 0, stream>>>(
            edge_index, etype, r_index, h, (int*)d_out, gcnt, store,
            capr, B, N, E, nchunk, nbkt);
        phase2_kernel<<<nbkt, TH2, 0, stream>>>(
            h, store, gcnt, capr, N, nchunk, (int*)d_out);
    } else {
        traverse_direct<<<(E + 255) / 256, 256, 0, stream>>>(
            h, edge_index, etype, r_index, (int*)d_out, B, N, E);
    }
}

// Round 6
// 39.240 us; speedup vs baseline: 1.7206x; 1.2298x over previous
//
#include <hip/hip_runtime.h>

// SymbolicTraversal: out[b, n] = max(0, max_{e: type[e]==r_index[b], dst[e]==n} h[b, src[e]])
//
// R5: two-phase, ZERO global atomics / counters in the fast path.
//   Storage: store[bkt][block] = one 64B segment: word0 = count (<=15), words 1..15 = records.
//   Each segment is written by exactly one (block,bucket) pair -> no atomics, no zeroing.
//   Phase1: stream edges (grid-stride, NB1 blocks), filter via relation->batch bitmask,
//           stage records in per-bucket LDS queues, flush each bucket as ONE full 64B line
//           (16 lanes x 4 buckets per wave-op).
//   Phase2: one block per bucket; segments for bucket k are contiguous (32KB); resolve
//           max in a 32KB LDS slice with ds-atomics; merge-write to pre-zeroed out.
//   Overflow (>15 records per (block,bucket), ~0.3% of segments): direct atomicMax into
//   out (pre-zeroed), merged by phase2 -> exact for any data.
// Record: ((dst & 8191) << 17) | src  (needs N <= 2^17, guarded).

typedef int v4i __attribute__((ext_vector_type(4)));

#define NB1 512
#define TH1 512
#define TH2 512
#define QCAP 15
#define CSHIFT 13
#define MAXNBKT 512

__global__ __launch_bounds__(256)
void zero_out_kernel(int* __restrict__ out, int n) {
    int i = (blockIdx.x * 256 + threadIdx.x) * 4;
    if (i + 3 < n) {
        v4i z = {0, 0, 0, 0};
        *reinterpret_cast<v4i*>(out + i) = z;
    } else {
        for (int j = i; j < n && j >= 0; ++j) out[j] = 0;
    }
}

__global__ __launch_bounds__(TH1)
void phase1_kernel(const int* __restrict__ edge_index, // [2][E]
                   const int* __restrict__ etype,      // [E]
                   const int* __restrict__ r_index,    // [B]
                   const float* __restrict__ h,
                   int* __restrict__ out,              // overflow fallback only
                   unsigned int* __restrict__ store,   // [nbkt][NB1][16] u32
                   int B, int N, int E, int nchunk, int nbkt) {
    __shared__ unsigned int smask[64];
    __shared__ unsigned int lcnt[MAXNBKT];
    __shared__ unsigned int lq[MAXNBKT * QCAP];

    const int t = threadIdx.x;
    if (t < 64) {
        unsigned int m = 0;
        for (int b = 0; b < B; ++b)
            if (r_index[b] == t) m |= (1u << b);
        smask[t] = m;
    }
    for (int i = t; i < nbkt; i += TH1) lcnt[i] = 0;
    __syncthreads();

    const int* __restrict__ src = edge_index;
    const int* __restrict__ dst = edge_index + E;
    const unsigned int cmask = (1u << CSHIFT) - 1u;
    const int nq = E >> 2;

    for (int q = blockIdx.x * TH1 + t; q < nq; q += NB1 * TH1) {
        v4i tv = __builtin_nontemporal_load(reinterpret_cast<const v4i*>(etype) + q);
        v4i sv = __builtin_nontemporal_load(reinterpret_cast<const v4i*>(src) + q);
        v4i dv = __builtin_nontemporal_load(reinterpret_cast<const v4i*>(dst) + q);
        #pragma unroll
        for (int i = 0; i < 4; ++i) {
            unsigned int ty = (unsigned int)tv[i];
            unsigned int m = (ty < 64u) ? smask[ty] : 0u;
            if (!m) continue;
            unsigned int d = (unsigned int)dv[i];
            unsigned int s = (unsigned int)sv[i];
            unsigned int rec = ((d & cmask) << 17) | s;
            int cb = (int)(d >> CSHIFT);
            do {
                int b = __builtin_ctz(m); m &= m - 1;
                int bkt = b * nchunk + cb;
                unsigned int pos = atomicAdd(&lcnt[bkt], 1u);
                if (pos < QCAP) {
                    lq[bkt * QCAP + pos] = rec;
                } else {
                    float v = h[(size_t)b * N + s];
                    atomicMax(out + (size_t)b * N + d, __float_as_int(v));
                }
            } while (m);
        }
    }
    // tail edges (E % 4), block 0 only
    if (blockIdx.x == 0) {
        for (int e = (nq << 2) + t; e < E; e += TH1) {
            unsigned int ty = (unsigned int)etype[e];
            unsigned int m = (ty < 64u) ? smask[ty] : 0u;
            unsigned int d = (unsigned int)dst[e];
            unsigned int s = (unsigned int)src[e];
            unsigned int rec = ((d & cmask) << 17) | s;
            int cb = (int)(d >> CSHIFT);
            while (m) {
                int b = __builtin_ctz(m); m &= m - 1;
                int bkt = b * nchunk + cb;
                unsigned int pos = atomicAdd(&lcnt[bkt], 1u);
                if (pos < QCAP) {
                    lq[bkt * QCAP + pos] = rec;
                } else {
                    float v = h[(size_t)b * N + s];
                    atomicMax(out + (size_t)b * N + d, __float_as_int(v));
                }
            }
        }
    }

    __syncthreads();
    // Flush: each bucket -> one full 64B line. 16 lanes per bucket, 4 buckets per wave.
    const int wid = t >> 6, lane = t & 63;
    const int sub = lane >> 4;       // 0..3: bucket within wave group
    const int word = lane & 15;      // 0..15: word within segment
    const unsigned int bid = blockIdx.x;
    for (int k0 = wid * 4; k0 < nbkt; k0 += (TH1 / 64) * 4) {
        int k = k0 + sub;
        if (k < nbkt) {
            unsigned int n = lcnt[k]; if (n > QCAP) n = QCAP;
            unsigned int val = (word == 0) ? n : lq[k * QCAP + (word - 1)];
            store[((size_t)k * NB1 + bid) * 16 + word] = val;
        }
    }
}

__global__ __launch_bounds__(TH2)
void phase2_kernel(const float* __restrict__ h,
                   const unsigned int* __restrict__ store,
                   int N, int nchunk,
                   int* __restrict__ out) {
    __shared__ int slice[1 << CSHIFT];  // 32KB

    const int t = threadIdx.x;
    const int k = blockIdx.x;           // bucket
    const int b = k / nchunk;
    const int c = k % nchunk;
    const int csz = 1 << CSHIFT;

    for (int i = t; i < csz; i += TH2) slice[i] = 0;
    __syncthreads();

    const unsigned int* __restrict__ base = store + (size_t)k * NB1 * 16;
    const float* __restrict__ hb = h + (size_t)b * N;

    // One segment per thread (NB1 == TH2). Lane reads word0 of consecutive 64B
    // segments (line-granule fetch); record reads then hit the hot line.
    for (int r = t; r < NB1; r += TH2) {
        const unsigned int* __restrict__ seg = base + (size_t)r * 16;
        unsigned int n = seg[0]; if (n > QCAP) n = QCAP;
        for (unsigned int i = 1; i <= n; ++i) {
            unsigned int rec = seg[i];
            int s  = (int)(rec & 0x1FFFFu);
            int ld = (int)(rec >> 17);
            float v = hb[s];
            atomicMax(&slice[ld], __float_as_int(v));  // LDS atomic
        }
    }
    __syncthreads();

    const int d0 = c << CSHIFT;
    int cnt = N - d0; if (cnt > csz) cnt = csz;
    int* __restrict__ ob = out + (size_t)b * N + d0;
    for (int i = t; i < cnt; i += TH2) {
        int cur = ob[i];          // pre-zeroed; holds overflow-fallback maxima
        int v = slice[i];
        ob[i] = cur > v ? cur : v;
    }
}

// Fallback for unsupported shapes (N > 2^17, B > 32, nbkt > MAXNBKT, small ws).
__global__ __launch_bounds__(256)
void traverse_direct(const float* __restrict__ h,
                     const int* __restrict__ edge_index,
                     const int* __restrict__ etype,
                     const int* __restrict__ r_index,
                     int* __restrict__ out, int B, int N, int E) {
    __shared__ unsigned int smask[64];
    if (threadIdx.x < 64) {
        unsigned int m = 0;
        for (int b = 0; b < B; ++b)
            if (r_index[b] == (int)threadIdx.x) m |= (1u << b);
        smask[threadIdx.x] = m;
    }
    __syncthreads();
    const int* __restrict__ src = edge_index;
    const int* __restrict__ dst = edge_index + E;
    int e = blockIdx.x * blockDim.x + threadIdx.x;
    if (e < E) {
        unsigned int ty = (unsigned int)etype[e];
        unsigned int m = (ty < 64u) ? smask[ty] : 0u;
        while (m) {
            int b = __builtin_ctz(m); m &= m - 1;
            float v = h[(size_t)b * N + src[e]];
            atomicMax(out + (size_t)b * N + dst[e], __float_as_int(v));
        }
    }
}

extern "C" void kernel_launch(void* const* d_in, const int* in_sizes, int n_in,
                              void* d_out, int out_size, void* d_ws, size_t ws_size,
                              hipStream_t stream) {
    const float* h          = (const float*)d_in[0];
    const int*   edge_index = (const int*)d_in[1];
    const int*   etype      = (const int*)d_in[2];
    const int*   r_index    = (const int*)d_in[3];

    const int B = in_sizes[3];
    const int N = in_sizes[0] / B;
    const int E = in_sizes[2];

    const int nchunk = (N + (1 << CSHIFT) - 1) >> CSHIFT;
    const int nbkt = B * nchunk;
    const size_t need_ws = (size_t)nbkt * NB1 * 64;

    // zero out: clamp floor + empty segments + overflow-merge base
    const int nz = (out_size + 1023) / 1024;
    zero_out_kernel<<<nz, 256, 0, stream>>>((int*)d_out, out_size);

    const bool fast = (N <= (1 << 17)) && (B <= 32) && (nbkt >= 1) &&
                      (nbkt <= MAXNBKT) && (ws_size >= need_ws) && (E >= 4);
    if (fast) {
        unsigned int* store = (unsigned int*)d_ws;
        phase1_kernel<<<NB1, TH1, 0, stream>>>(
            edge_index, etype, r_index, h, (int*)d_out, store,
            B, N, E, nchunk, nbkt);
        phase2_kernel<<<nbkt, TH2, 0, stream>>>(
            h, store, N, nchunk, (int*)d_out);
    } else {
        traverse_direct<<<(E + 255) / 256, 256, 0, stream>>>(
            h, edge_index, etype, r_index, (int*)d_out, B, N, E);
    }
}